// Round 1
// baseline (291.001 us; speedup 1.0000x reference)
//
#include <hip/hip_runtime.h>

// Volume renderer: alpha-compositing over 192 samples per ray.
// One 64-lane wave per ray; lane l owns 3 CONTIGUOUS samples {3l, 3l+1, 3l+2}.
//
// v2 changes vs v1 (102 us/dispatch, VGPR=20, latency-bound):
//  * ALL 16 input floats loaded up front -> batched global loads (MLP) instead
//    of the serialized load->wait->consume chain forced by VGPR=20.
//  * Product scan + 5 sum-reductions rewritten as gfx9 DPP scans
//    (row_shr:1/2/4/8 + row_bcast:15/31): 6 full-rate VALU ops per value
//    instead of 6 ds_bpermute (~64cy LDS-pipe latency each). 37 ds ops -> 1.
//  * Boundary depth comes from a 4th (clamped) depth load, not __shfl_down.
//  * Reduction result naturally lands in lane 63 -> lane 63 stores.

#define NRAYS 65536
#define L 192
#define BORDER_W 1e10f
#define EPS_F 1e-10f

// DPP helper: invalid-source / masked-row lanes receive `old` (identity).
template <int CTRL, int RMASK>
__device__ __forceinline__ float updpp(float old, float src) {
    return __int_as_float(__builtin_amdgcn_update_dpp(
        __float_as_int(old), __float_as_int(src), CTRL, RMASK, 0xf, false));
}

// Inclusive product scan across the 64-lane wave (6 DPP VALU ops).
__device__ __forceinline__ float wave_incl_prod(float p) {
    p *= updpp<0x111, 0xf>(1.0f, p);  // row_shr:1
    p *= updpp<0x112, 0xf>(1.0f, p);  // row_shr:2
    p *= updpp<0x114, 0xf>(1.0f, p);  // row_shr:4
    p *= updpp<0x118, 0xf>(1.0f, p);  // row_shr:8
    p *= updpp<0x142, 0xa>(1.0f, p);  // row_bcast:15 -> rows 1,3
    p *= updpp<0x143, 0xc>(1.0f, p);  // row_bcast:31 -> rows 2,3
    return p;
}

// Inclusive sum scan: after this, lane 63 holds the wave total.
#define SUMSCAN(v)                          \
    v += updpp<0x111, 0xf>(0.0f, v);        \
    v += updpp<0x112, 0xf>(0.0f, v);        \
    v += updpp<0x114, 0xf>(0.0f, v);        \
    v += updpp<0x118, 0xf>(0.0f, v);        \
    v += updpp<0x142, 0xa>(0.0f, v);        \
    v += updpp<0x143, 0xc>(0.0f, v);

__device__ __forceinline__ float fast_sigmoid(float x) {
    return __builtin_amdgcn_rcpf(1.0f + __expf(-x));
}

__global__ __launch_bounds__(256) void vol_render_kernel(
    const float* __restrict__ depth,   // [N, 192]
    const float* __restrict__ rgb,     // [N, 192, 3]
    const float* __restrict__ sigma,   // [N, 192]
    float* __restrict__ out)           // color N*3 | depth N | acc N | weights N*192
{
    const int lane = threadIdx.x & 63;
    const int wave = threadIdx.x >> 6;
    const int ray  = blockIdx.x * (blockDim.x >> 6) + wave;
    if (ray >= NRAYS) return;

    const size_t sbase = (size_t)ray * L + lane * 3;

    // ---- ALL input loads issued up front, back-to-back (MLP) ----
    float d0 = depth[sbase], d1 = depth[sbase + 1], d2 = depth[sbase + 2];
    // boundary depth: next sample's depth via a clamped 4th load (no shuffle).
    // For lane 63 the value is unused (border); clamp only guards the very
    // last element of the whole buffer.
    size_t i3 = sbase + 3;
    if (i3 > (size_t)NRAYS * L - 1) i3 = (size_t)NRAYS * L - 1;
    float d3 = depth[i3];

    float s0 = sigma[sbase], s1 = sigma[sbase + 1], s2 = sigma[sbase + 2];

    const float* rp = rgb + (size_t)ray * (L * 3) + lane * 9;
    float r0 = rp[0], r1 = rp[1], r2 = rp[2];
    float r3 = rp[3], r4 = rp[4], r5 = rp[5];
    float r6 = rp[6], r7 = rp[7], r8 = rp[8];

    // ---- alpha / survival ----
    float delta0 = d1 - d0;
    float delta1 = d2 - d1;
    float delta2 = (lane == 63) ? BORDER_W : (d3 - d2);

    float e0 = __expf(-fmaxf(s0, 0.0f) * delta0);
    float e1 = __expf(-fmaxf(s1, 0.0f) * delta1);
    float e2 = __expf(-fmaxf(s2, 0.0f) * delta2);
    float surv0 = e0 + EPS_F, surv1 = e1 + EPS_F, surv2 = e2 + EPS_F;

    // in-lane prefix products
    float p01  = surv0 * surv1;
    float p012 = p01 * surv2;

    // sigmoids: independent of the scan -> scheduler interleaves them
    float g0 = fast_sigmoid(r0), g1 = fast_sigmoid(r1), g2 = fast_sigmoid(r2);
    float g3 = fast_sigmoid(r3), g4 = fast_sigmoid(r4), g5 = fast_sigmoid(r5);
    float g6 = fast_sigmoid(r6), g7 = fast_sigmoid(r7), g8 = fast_sigmoid(r8);

    // ---- wave-wide inclusive product scan (DPP, VALU-only) ----
    float p = wave_incl_prod(p012);

    // exclusive: single remaining cross-lane op
    float excl = __shfl_up(p, 1, 64);
    if (lane == 0) excl = 1.0f;

    // transmittance & weights for the 3 owned samples
    float T0 = excl;
    float T1 = excl * surv0;
    float T2 = excl * p01;
    float w0 = (1.0f - e0) * T0;
    float w1 = (1.0f - e1) * T1;
    float w2 = (1.0f - e2) * T2;

    // coalesced weight store (wave covers contiguous 768 B)
    float* wptr = out + (size_t)NRAYS * 5 + sbase;
    wptr[0] = w0; wptr[1] = w1; wptr[2] = w2;

    float col0 = w0 * g0 + w1 * g3 + w2 * g6;
    float col1 = w0 * g1 + w1 * g4 + w2 * g7;
    float col2 = w0 * g2 + w1 * g5 + w2 * g8;
    float dep  = w0 * d0 + w1 * d1 + w2 * d2;
    float acc  = w0 + w1 + w2;

    // ---- 5 wave sums via DPP sum-scan; totals land in lane 63 ----
    SUMSCAN(col0)
    SUMSCAN(col1)
    SUMSCAN(col2)
    SUMSCAN(dep)
    SUMSCAN(acc)

    if (lane == 63) {
        out[(size_t)ray * 3 + 0] = col0;
        out[(size_t)ray * 3 + 1] = col1;
        out[(size_t)ray * 3 + 2] = col2;
        out[(size_t)NRAYS * 3 + ray] = dep;
        out[(size_t)NRAYS * 4 + ray] = acc;
    }
}

extern "C" void kernel_launch(void* const* d_in, const int* in_sizes, int n_in,
                              void* d_out, int out_size, void* d_ws, size_t ws_size,
                              hipStream_t stream) {
    const float* depth = (const float*)d_in[0];
    const float* rgb   = (const float*)d_in[1];
    const float* sigma = (const float*)d_in[2];
    float* out = (float*)d_out;

    // 4 waves (rays) per 256-thread block
    const int rays_per_block = 4;
    dim3 grid(NRAYS / rays_per_block);
    dim3 block(256);
    vol_render_kernel<<<grid, block, 0, stream>>>(depth, rgb, sigma, out);
}

// Round 2
// 290.766 us; speedup vs baseline: 1.0008x; 1.0008x over previous
//
#include <hip/hip_runtime.h>

// Volume renderer: alpha-compositing over 192 samples per ray.
// One 64-lane wave per ray; lane l (l<48) owns 4 CONTIGUOUS samples {4l..4l+3}.
//
// v3 changes vs v2 (103 us/dispatch, VGPR=20 -- compiler re-serialized the
// 16 scalar loads, so nothing changed):
//  * Re-tiled 3 samples/lane -> 4 samples/lane (48 active lanes) so EVERY
//    input access is an indivisible float4 (global_load_dwordx4):
//      depth 1x, sigma 1x, rgb 3x, +1 scalar boundary depth = 6 load
//    instructions instead of 16 scalar ones. The compiler cannot split a
//    dwordx4, so the loads stay in flight together (VGPR must rise to ~40+).
//  * Each load is perfectly coalesced: 16B/lane contiguous (vs 4B at 12B
//    stride before).
//  * Weights written as one float4 store.
//  * Lanes 48-63 carry identity values (p=1, sums=0) through the 64-lane
//    DPP scans; lane 63 stores the reductions.

#define NRAYS 65536
#define L 192
#define BORDER_W 1e10f
#define EPS_F 1e-10f

// DPP helper: invalid-source / masked-row lanes receive `old` (identity).
template <int CTRL, int RMASK>
__device__ __forceinline__ float updpp(float old, float src) {
    return __int_as_float(__builtin_amdgcn_update_dpp(
        __float_as_int(old), __float_as_int(src), CTRL, RMASK, 0xf, false));
}

// Inclusive product scan across the 64-lane wave (6 DPP VALU ops).
__device__ __forceinline__ float wave_incl_prod(float p) {
    p *= updpp<0x111, 0xf>(1.0f, p);  // row_shr:1
    p *= updpp<0x112, 0xf>(1.0f, p);  // row_shr:2
    p *= updpp<0x114, 0xf>(1.0f, p);  // row_shr:4
    p *= updpp<0x118, 0xf>(1.0f, p);  // row_shr:8
    p *= updpp<0x142, 0xa>(1.0f, p);  // row_bcast:15 -> rows 1,3
    p *= updpp<0x143, 0xc>(1.0f, p);  // row_bcast:31 -> rows 2,3
    return p;
}

// Inclusive sum scan: after this, lane 63 holds the wave total.
#define SUMSCAN(v)                          \
    v += updpp<0x111, 0xf>(0.0f, v);        \
    v += updpp<0x112, 0xf>(0.0f, v);        \
    v += updpp<0x114, 0xf>(0.0f, v);        \
    v += updpp<0x118, 0xf>(0.0f, v);        \
    v += updpp<0x142, 0xa>(0.0f, v);        \
    v += updpp<0x143, 0xc>(0.0f, v);

__device__ __forceinline__ float fast_sigmoid(float x) {
    return __builtin_amdgcn_rcpf(1.0f + __expf(-x));
}

__global__ __launch_bounds__(256) void vol_render_kernel(
    const float* __restrict__ depth,   // [N, 192]
    const float* __restrict__ rgb,     // [N, 192, 3]
    const float* __restrict__ sigma,   // [N, 192]
    float* __restrict__ out)           // color N*3 | depth N | acc N | weights N*192
{
    const int lane = threadIdx.x & 63;
    const int wave = threadIdx.x >> 6;
    const int ray  = blockIdx.x * (blockDim.x >> 6) + wave;
    if (ray >= NRAYS) return;

    const bool active = lane < 48;
    const size_t sbase = (size_t)ray * L + lane * 4;   // valid only for active lanes

    // identity values for inactive lanes: sigma=0 -> e=1 -> w=0, sums=0
    float4 dv = make_float4(0.f, 0.f, 0.f, 0.f);
    float4 sv = make_float4(0.f, 0.f, 0.f, 0.f);
    float4 rv0 = make_float4(0.f, 0.f, 0.f, 0.f);
    float4 rv1 = make_float4(0.f, 0.f, 0.f, 0.f);
    float4 rv2 = make_float4(0.f, 0.f, 0.f, 0.f);
    float d4 = 0.f;

    if (active) {
        // ---- 6 vector-load instructions, all 16B/lane coalesced ----
        dv = *reinterpret_cast<const float4*>(depth + sbase);
        sv = *reinterpret_cast<const float4*>(sigma + sbase);
        const float* rp = rgb + (size_t)ray * (L * 3) + lane * 12;
        rv0 = *reinterpret_cast<const float4*>(rp + 0);
        rv1 = *reinterpret_cast<const float4*>(rp + 4);
        rv2 = *reinterpret_cast<const float4*>(rp + 8);
        // boundary depth: sample 4l+4 (lane 47's is the border -> unused).
        size_t i4 = sbase + 4;
        if (i4 > (size_t)NRAYS * L - 1) i4 = (size_t)NRAYS * L - 1;
        d4 = depth[i4];
    }

    // ---- alpha / survival ----
    float delta0 = dv.y - dv.x;
    float delta1 = dv.z - dv.y;
    float delta2 = dv.w - dv.z;
    float delta3 = (lane == 47) ? BORDER_W : (d4 - dv.w);

    float e0 = __expf(-fmaxf(sv.x, 0.0f) * delta0);
    float e1 = __expf(-fmaxf(sv.y, 0.0f) * delta1);
    float e2 = __expf(-fmaxf(sv.z, 0.0f) * delta2);
    float e3 = __expf(-fmaxf(sv.w, 0.0f) * delta3);
    float surv0 = e0 + EPS_F, surv1 = e1 + EPS_F;
    float surv2 = e2 + EPS_F, surv3 = e3 + EPS_F;

    // in-lane prefix products
    float p01   = surv0 * surv1;
    float p012  = p01 * surv2;
    float p0123 = p012 * surv3;

    // sigmoids: independent of the scan -> scheduler interleaves them
    float g0 = fast_sigmoid(rv0.x), g1 = fast_sigmoid(rv0.y), g2 = fast_sigmoid(rv0.z);
    float g3 = fast_sigmoid(rv0.w), g4 = fast_sigmoid(rv1.x), g5 = fast_sigmoid(rv1.y);
    float g6 = fast_sigmoid(rv1.z), g7 = fast_sigmoid(rv1.w), g8 = fast_sigmoid(rv2.x);
    float g9 = fast_sigmoid(rv2.y), gA = fast_sigmoid(rv2.z), gB = fast_sigmoid(rv2.w);

    // ---- wave-wide inclusive product scan (DPP, VALU-only) ----
    // inactive lanes contribute ~1.0; they sit above lane 47 so they never
    // affect active lanes' prefixes.
    float p = wave_incl_prod(p0123);

    // exclusive: single remaining cross-lane op
    float excl = __shfl_up(p, 1, 64);
    if (lane == 0) excl = 1.0f;

    // transmittance & weights for the 4 owned samples
    float T0 = excl;
    float T1 = excl * surv0;
    float T2 = excl * p01;
    float T3 = excl * p012;
    float w0 = (1.0f - e0) * T0;
    float w1 = (1.0f - e1) * T1;
    float w2 = (1.0f - e2) * T2;
    float w3 = (1.0f - e3) * T3;

    // coalesced float4 weight store
    if (active) {
        float4 wv = make_float4(w0, w1, w2, w3);
        *reinterpret_cast<float4*>(out + (size_t)NRAYS * 5 + sbase) = wv;
    }

    float col0 = w0 * g0 + w1 * g3 + w2 * g6 + w3 * g9;
    float col1 = w0 * g1 + w1 * g4 + w2 * g7 + w3 * gA;
    float col2 = w0 * g2 + w1 * g5 + w2 * g8 + w3 * gB;
    float dep  = w0 * dv.x + w1 * dv.y + w2 * dv.z + w3 * dv.w;
    float acc  = w0 + w1 + w2 + w3;

    // ---- 5 wave sums via DPP sum-scan; totals land in lane 63 ----
    SUMSCAN(col0)
    SUMSCAN(col1)
    SUMSCAN(col2)
    SUMSCAN(dep)
    SUMSCAN(acc)

    if (lane == 63) {
        out[(size_t)ray * 3 + 0] = col0;
        out[(size_t)ray * 3 + 1] = col1;
        out[(size_t)ray * 3 + 2] = col2;
        out[(size_t)NRAYS * 3 + ray] = dep;
        out[(size_t)NRAYS * 4 + ray] = acc;
    }
}

extern "C" void kernel_launch(void* const* d_in, const int* in_sizes, int n_in,
                              void* d_out, int out_size, void* d_ws, size_t ws_size,
                              hipStream_t stream) {
    const float* depth = (const float*)d_in[0];
    const float* rgb   = (const float*)d_in[1];
    const float* sigma = (const float*)d_in[2];
    float* out = (float*)d_out;

    // 4 waves (rays) per 256-thread block
    const int rays_per_block = 4;
    dim3 grid(NRAYS / rays_per_block);
    dim3 block(256);
    vol_render_kernel<<<grid, block, 0, stream>>>(depth, rgb, sigma, out);
}